// Round 7
// baseline (54.828 us; speedup 1.0000x reference)
//
#include <hip/hip_runtime.h>

#define WINDOW 10
#define TDIM 4096
#define TVALID (TDIM - WINDOW)   // 4086 valid outputs per row
#define WSTRIDE 4160             // padded bf16 row stride in ws (4096 + 64 pad)

typedef __attribute__((ext_vector_type(8)))  short bf16x8;   // MFMA operand (4 VGPRs)
typedef __attribute__((ext_vector_type(8)))  __bf16 bfv8;
typedef __attribute__((ext_vector_type(8)))  float f32x8;
typedef __attribute__((ext_vector_type(16))) float f32x16;
typedef __attribute__((ext_vector_type(2)))  float f32x2;
typedef __attribute__((ext_vector_type(4)))  unsigned u32x4;
typedef float f32x4u __attribute__((ext_vector_type(4), aligned(4)));
typedef short s16x8u __attribute__((ext_vector_type(8), aligned(2)));  // unaligned bf16 load

static __device__ __forceinline__ short f2bf(float f) {
  return (short)__builtin_bit_cast(unsigned short, (__bf16)f);   // RNE
}

// layer-2 relu-dot: scalar v_max + packed v_pk_fma_f32
static __device__ __forceinline__ float l2dot(const f32x16& acc, const f32x2* __restrict__ w2p) {
  f32x2 s0 = {0.f, 0.f}, s1 = {0.f, 0.f};
  #pragma unroll
  for (int j = 0; j < 8; j += 2) {
    f32x2 a, b;
    a[0] = fmaxf(acc[2*j],     0.f); a[1] = fmaxf(acc[2*j + 1], 0.f);
    b[0] = fmaxf(acc[2*j + 2], 0.f); b[1] = fmaxf(acc[2*j + 3], 0.f);
    s0 = __builtin_elementwise_fma(a, w2p[j],     s0);
    s1 = __builtin_elementwise_fma(b, w2p[j + 1], s1);
  }
  f32x2 s = s0 + s1;
  return s[0] + s[1];
}

static __device__ __forceinline__ float combine_halves(float Pe, float Po, int lid) {
#if __has_builtin(__builtin_amdgcn_permlane32_swap)
  auto r = __builtin_amdgcn_permlane32_swap(
      __builtin_bit_cast(unsigned, Pe), __builtin_bit_cast(unsigned, Po), false, false);
  return __builtin_bit_cast(float, (unsigned)r[0]) + __builtin_bit_cast(float, (unsigned)r[1]);
#else
  Pe += __shfl_xor(Pe, 32, 64);
  Po += __shfl_xor(Po, 32, 64);
  return (lid < 32) ? Pe : Po;
#endif
}

static __device__ __forceinline__ float half_sigmoid(float z) {
  float e = __expf(-z);
#if __has_builtin(__builtin_amdgcn_rcpf)
  return 0.5f * __builtin_amdgcn_rcpf(1.0f + e);
#else
  return 0.5f / (1.0f + e);
#endif
}

// ---------------- kernel 1: f32 -> padded bf16 rows in ws ----------------
__global__ __launch_bounds__(256) void prestage(const float* __restrict__ ret,
                                                unsigned short* __restrict__ ws) {
  const int row = blockIdx.x;
  const float* __restrict__ rowp = ret + (size_t)row * TDIM;
  unsigned short* __restrict__ wrow = ws + (size_t)row * WSTRIDE;
  const float last = rowp[TDIM - 1];
  for (int c = threadIdx.x; c < WSTRIDE / 8; c += 256) {
    f32x8 f;
    if (c < TDIM / 8) {
      f32x4u a = *(const f32x4u*)(rowp + 8 * c);
      f32x4u b = *(const f32x4u*)(rowp + 8 * c + 4);
      f[0]=a[0]; f[1]=a[1]; f[2]=a[2]; f[3]=a[3];
      f[4]=b[0]; f[5]=b[1]; f[6]=b[2]; f[7]=b[3];
    } else {
      for (int j = 0; j < 8; ++j) f[j] = last;   // replicate-pad == old clamp
    }
    bfv8 h = __builtin_convertvector(f, bfv8);
    *(bf16x8*)(wrow + 8 * c) = __builtin_bit_cast(bf16x8, h);   // 16B-aligned store
  }
}

// ---------------- shared setup ----------------
struct Setup {
  bf16x8 af; f32x2 w2p[8]; float b2c;
  int lid, n, g; bool g1;
};
static __device__ __forceinline__ Setup make_setup(
    const float* __restrict__ W1, const float* __restrict__ b1,
    const float* __restrict__ W2, const float* __restrict__ b2) {
  Setup s;
  s.lid = threadIdx.x & 63; s.n = s.lid & 31; s.g = s.lid >> 5; s.g1 = (s.g == 1);
  if (!s.g1) {
    #pragma unroll
    for (int j = 0; j < 8; ++j) s.af[j] = f2bf(W1[s.n * WINDOW + j]);
  } else {
    s.af[0] = f2bf(W1[s.n * WINDOW + 8]);
    s.af[1] = f2bf(W1[s.n * WINDOW + 9]);
    s.af[2] = f2bf(b1[s.n]);                 // bias at k-slot 10
    #pragma unroll
    for (int j = 3; j < 8; ++j) s.af[j] = 0; // B k=11..15 don't-cares
  }
  #pragma unroll
  for (int j = 0; j < 8; ++j) {
    s.w2p[j][0] = W2[((2*j)   & 3) + 8 * ((2*j)   >> 2) + 4 * s.g];
    s.w2p[j][1] = W2[((2*j+1) & 3) + 8 * ((2*j+1) >> 2) + 4 * s.g];
  }
  s.b2c = b2[0];
  return s;
}

// ---------------- main-kernel tile-pair body (bf16 path) ----------------
static __device__ __forceinline__ float pair_bf(
    const Setup& S, const unsigned short* __restrict__ lanep, int p,
    unsigned andm, unsigned orm) {
  s16x8u ve = *(const s16x8u*)(lanep + p * 64);
  s16x8u vo = *(const s16x8u*)(lanep + p * 64 + 32);
  u32x4 ue = __builtin_bit_cast(u32x4, ve);
  u32x4 uo = __builtin_bit_cast(u32x4, vo);
  ue[1] = (ue[1] & andm) | orm;    // v_and_or_b32: set bias slot to bf16(1.0) on g1
  uo[1] = (uo[1] & andm) | orm;
  f32x16 acce = {}, acco = {};
  acce = __builtin_amdgcn_mfma_f32_32x32x16_bf16(S.af, __builtin_bit_cast(bf16x8, ue), acce, 0, 0, 0);
  acco = __builtin_amdgcn_mfma_f32_32x32x16_bf16(S.af, __builtin_bit_cast(bf16x8, uo), acco, 0, 0, 0);
  float Pe = l2dot(acce, S.w2p);
  float Po = l2dot(acco, S.w2p);
  const float q = combine_halves(Pe, Po, S.lid);
  return half_sigmoid(q + S.b2c);
}

// ---------------- kernel 2: main, bf16 fragments straight from ws ----------------
__global__ __launch_bounds__(256) void hurst_main_bf(
    const unsigned short* __restrict__ ws, const float* __restrict__ W1,
    const float* __restrict__ b1,  const float* __restrict__ W2,
    const float* __restrict__ b2,  float* __restrict__ out) {
  Setup S = make_setup(W1, b1, W2, b2);
  const int wv  = threadIdx.x >> 6;
  const int row = blockIdx.x;
  const int seg = wv * 1024;
  const unsigned andm = S.g1 ? 0xFFFF0000u : 0xFFFFFFFFu;
  const unsigned orm  = S.g1 ? 0x00003F80u : 0u;

  const unsigned short* __restrict__ lanep = ws + (size_t)row * WSTRIDE + seg + S.n + 8 * S.g;
  float* __restrict__ orow = out + (size_t)row * TDIM;

  float y = pair_bf(S, lanep, 0, andm, orm);
  orow[WINDOW + seg + S.lid] = y;
  if (wv == 0) {                         // head broadcast, once per block
    const float y0 = __shfl(y, 0, 64);
    if (S.lid < WINDOW) orow[S.lid] = y0;
  }
  #pragma unroll
  for (int p = 1; p < 15; ++p) {
    y = pair_bf(S, lanep, p, andm, orm);
    orow[WINDOW + seg + p * 64 + S.lid] = y;
  }
  y = pair_bf(S, lanep, 15, andm, orm);  // loads hit replicate-pad; mask stores
  const int t = seg + 15 * 64 + S.lid;
  if (t < TVALID) orow[WINDOW + t] = y;
}

// ---------------- fallback: f32 loads + inline cvt (no ws needed) ----------------
static __device__ __forceinline__ f32x8 ld8(const float* __restrict__ p) {
  f32x4u a = *(const f32x4u*)p;
  f32x4u b = *(const f32x4u*)(p + 4);
  f32x8 f; f[0]=a[0];f[1]=a[1];f[2]=a[2];f[3]=a[3];f[4]=b[0];f[5]=b[1];f[6]=b[2];f[7]=b[3];
  return f;
}
static __device__ __forceinline__ bf16x8 packbf(f32x8 f, bool g1) {
  f[2] = g1 ? 1.0f : f[2];
  return __builtin_bit_cast(bf16x8, __builtin_convertvector(f, bfv8));
}
static __device__ __forceinline__ float pair_f32(
    const Setup& S, const float* __restrict__ rowp, int seg, int p, bool clamp) {
  const int lbase = S.n + 8 * S.g;
  f32x8 fe = ld8(rowp + seg + p * 64 + lbase);
  f32x8 fo;
  if (clamp) {
    for (int j = 0; j < 8; ++j) {
      int idx = seg + p * 64 + 32 + lbase + j;
      idx = idx < TDIM - 1 ? idx : TDIM - 1;
      fo[j] = rowp[idx];
    }
  } else {
    fo = ld8(rowp + seg + p * 64 + 32 + lbase);
  }
  bf16x8 bve = packbf(fe, S.g1), bvo = packbf(fo, S.g1);
  f32x16 acce = {}, acco = {};
  acce = __builtin_amdgcn_mfma_f32_32x32x16_bf16(S.af, bve, acce, 0, 0, 0);
  acco = __builtin_amdgcn_mfma_f32_32x32x16_bf16(S.af, bvo, acco, 0, 0, 0);
  float Pe = l2dot(acce, S.w2p);
  float Po = l2dot(acco, S.w2p);
  const float q = combine_halves(Pe, Po, S.lid);
  return half_sigmoid(q + S.b2c);
}
__global__ __launch_bounds__(256) void hurst_main_f32(
    const float* __restrict__ ret, const float* __restrict__ W1,
    const float* __restrict__ b1,  const float* __restrict__ W2,
    const float* __restrict__ b2,  float* __restrict__ out) {
  Setup S = make_setup(W1, b1, W2, b2);
  const int wv  = threadIdx.x >> 6;
  const int row = blockIdx.x;
  const int seg = wv * 1024;
  const float* __restrict__ rowp = ret + (size_t)row * TDIM;
  float* __restrict__ orow = out + (size_t)row * TDIM;

  float y = pair_f32(S, rowp, seg, 0, false);
  orow[WINDOW + seg + S.lid] = y;
  if (wv == 0) { const float y0 = __shfl(y, 0, 64); if (S.lid < WINDOW) orow[S.lid] = y0; }
  #pragma unroll
  for (int p = 1; p < 15; ++p) {
    y = pair_f32(S, rowp, seg, p, false);
    orow[WINDOW + seg + p * 64 + S.lid] = y;
  }
  y = pair_f32(S, rowp, seg, 15, wv == 3);
  const int t = seg + 15 * 64 + S.lid;
  if (t < TVALID) orow[WINDOW + t] = y;
}

extern "C" void kernel_launch(void* const* d_in, const int* in_sizes, int n_in,
                              void* d_out, int out_size, void* d_ws, size_t ws_size,
                              hipStream_t stream) {
  const float* ret = (const float*)d_in[0];
  const float* W1  = (const float*)d_in[1];
  const float* b1  = (const float*)d_in[2];
  const float* W2  = (const float*)d_in[3];
  const float* b2  = (const float*)d_in[4];
  float* out = (float*)d_out;

  const int B = in_sizes[0] / TDIM;     // 2048
  const size_t need = (size_t)B * WSTRIDE * sizeof(unsigned short);
  dim3 block(256);
  dim3 grid(B);
  if (ws_size >= need) {
    unsigned short* ws = (unsigned short*)d_ws;
    hipLaunchKernelGGL(prestage, grid, block, 0, stream, ret, ws);
    hipLaunchKernelGGL(hurst_main_bf, grid, block, 0, stream,
                       ws, W1, b1, W2, b2, out);
  } else {
    hipLaunchKernelGGL(hurst_main_f32, grid, block, 0, stream,
                       ret, W1, b1, W2, b2, out);
  }
}

// Round 8
// 47.054 us; speedup vs baseline: 1.1652x; 1.1652x over previous
//
#include <hip/hip_runtime.h>

#define WINDOW 10
#define TDIM 4096
#define TVALID (TDIM - WINDOW)   // 4086 valid outputs per row

typedef __attribute__((ext_vector_type(8)))  short bf16x8;   // MFMA operand (4 VGPRs)
typedef __attribute__((ext_vector_type(8)))  __bf16 bfv8;
typedef __attribute__((ext_vector_type(8)))  float f32x8;
typedef __attribute__((ext_vector_type(16))) float f32x16;
typedef __attribute__((ext_vector_type(2)))  float f32x2;
typedef float f32x4u __attribute__((ext_vector_type(4), aligned(4)));

static __device__ __forceinline__ short f2bf(float f) {
  return (short)__builtin_bit_cast(unsigned short, (__bf16)f);   // RNE
}

// layer-2 relu-dot: scalar v_max + packed v_pk_fma_f32
static __device__ __forceinline__ float l2dot(const f32x16& acc, const f32x2* __restrict__ w2p) {
  f32x2 s0 = {0.f, 0.f}, s1 = {0.f, 0.f};
  #pragma unroll
  for (int j = 0; j < 8; j += 2) {
    f32x2 a, b;
    a[0] = fmaxf(acc[2*j],     0.f); a[1] = fmaxf(acc[2*j + 1], 0.f);
    b[0] = fmaxf(acc[2*j + 2], 0.f); b[1] = fmaxf(acc[2*j + 3], 0.f);
    s0 = __builtin_elementwise_fma(a, w2p[j],     s0);
    s1 = __builtin_elementwise_fma(b, w2p[j + 1], s1);
  }
  f32x2 s = s0 + s1;
  return s[0] + s[1];
}

static __device__ __forceinline__ float combine_halves(float Pe, float Po, int lid) {
#if __has_builtin(__builtin_amdgcn_permlane32_swap)
  auto r = __builtin_amdgcn_permlane32_swap(
      __builtin_bit_cast(unsigned, Pe), __builtin_bit_cast(unsigned, Po), false, false);
  return __builtin_bit_cast(float, (unsigned)r[0]) + __builtin_bit_cast(float, (unsigned)r[1]);
#else
  Pe += __shfl_xor(Pe, 32, 64);
  Po += __shfl_xor(Po, 32, 64);
  return (lid < 32) ? Pe : Po;
#endif
}

static __device__ __forceinline__ float half_sigmoid(float z) {
  float e = __expf(-z);
#if __has_builtin(__builtin_amdgcn_rcpf)
  return 0.5f * __builtin_amdgcn_rcpf(1.0f + e);
#else
  return 0.5f / (1.0f + e);
#endif
}

struct Setup {
  bf16x8 af; f32x2 w2p[8]; float b2c;
  int lid, n, g; bool g1;
};
static __device__ __forceinline__ Setup make_setup(
    const float* __restrict__ W1, const float* __restrict__ b1,
    const float* __restrict__ W2, const float* __restrict__ b2) {
  Setup s;
  s.lid = threadIdx.x & 63; s.n = s.lid & 31; s.g = s.lid >> 5; s.g1 = (s.g == 1);
  if (!s.g1) {
    #pragma unroll
    for (int j = 0; j < 8; ++j) s.af[j] = f2bf(W1[s.n * WINDOW + j]);
  } else {
    s.af[0] = f2bf(W1[s.n * WINDOW + 8]);
    s.af[1] = f2bf(W1[s.n * WINDOW + 9]);
    s.af[2] = f2bf(b1[s.n]);                 // bias at k-slot 10
    #pragma unroll
    for (int j = 3; j < 8; ++j) s.af[j] = 0; // B k=11..15 don't-cares
  }
  #pragma unroll
  for (int j = 0; j < 8; ++j) {
    s.w2p[j][0] = W2[((2*j)   & 3) + 8 * ((2*j)   >> 2) + 4 * s.g];
    s.w2p[j][1] = W2[((2*j+1) & 3) + 8 * ((2*j+1) >> 2) + 4 * s.g];
  }
  s.b2c = b2[0];
  return s;
}

static __device__ __forceinline__ f32x8 ld8(const float* __restrict__ p) {
  f32x4u a = *(const f32x4u*)p;
  f32x4u b = *(const f32x4u*)(p + 4);
  f32x8 f; f[0]=a[0];f[1]=a[1];f[2]=a[2];f[3]=a[3];f[4]=b[0];f[5]=b[1];f[6]=b[2];f[7]=b[3];
  return f;
}
static __device__ __forceinline__ bf16x8 packbf(f32x8 f, bool g1) {
  f[2] = g1 ? 1.0f : f[2];           // bias column at k-slot 10
  return __builtin_bit_cast(bf16x8, __builtin_convertvector(f, bfv8));
}

// one tile-pair (64 outputs): 2 MFMAs + relu-dot + combine + sigmoid
static __device__ __forceinline__ float pair_f32(
    const Setup& S, const float* __restrict__ rowp, int seg, int p, bool clamp) {
  const int lbase = S.n + 8 * S.g;
  f32x8 fe = ld8(rowp + seg + p * 64 + lbase);
  f32x8 fo;
  if (clamp) {
    for (int j = 0; j < 8; ++j) {
      int idx = seg + p * 64 + 32 + lbase + j;
      idx = idx < TDIM - 1 ? idx : TDIM - 1;
      fo[j] = rowp[idx];
    }
  } else {
    fo = ld8(rowp + seg + p * 64 + 32 + lbase);
  }
  bf16x8 bve = packbf(fe, S.g1), bvo = packbf(fo, S.g1);
  f32x16 acce = {}, acco = {};
  acce = __builtin_amdgcn_mfma_f32_32x32x16_bf16(S.af, bve, acce, 0, 0, 0);
  acco = __builtin_amdgcn_mfma_f32_32x32x16_bf16(S.af, bvo, acco, 0, 0, 0);
  float Pe = l2dot(acce, S.w2p);
  float Po = l2dot(acco, S.w2p);
  const float q = combine_halves(Pe, Po, S.lid);
  return half_sigmoid(q + S.b2c);
}

// High-TLP mapping: each wave = 4 tile-pairs (256 t's); 8192 blocks.
__global__ __launch_bounds__(256) void hurst_tlp(
    const float* __restrict__ ret, const float* __restrict__ W1,
    const float* __restrict__ b1,  const float* __restrict__ W2,
    const float* __restrict__ b2,  float* __restrict__ out) {
  Setup S = make_setup(W1, b1, W2, b2);
  const int wv    = threadIdx.x >> 6;
  const int row   = blockIdx.x;
  const int chunk = blockIdx.y;              // 0..3, 1024-wide t-chunk
  const int seg   = chunk * 1024 + wv * 256; // this wave's 256-wide span

  const float* __restrict__ rowp = ret + (size_t)row * TDIM;
  float* __restrict__ orow = out + (size_t)row * TDIM;

  float y = pair_f32(S, rowp, seg, 0, false);
  orow[WINDOW + seg + S.lid] = y;
  if (chunk == 0 && wv == 0) {               // head broadcast, once per row
    const float y0 = __shfl(y, 0, 64);
    if (S.lid < WINDOW) orow[S.lid] = y0;
  }
  #pragma unroll
  for (int p = 1; p < 3; ++p) {
    y = pair_f32(S, rowp, seg, p, false);
    orow[WINDOW + seg + p * 64 + S.lid] = y;
  }
  const bool tail = (chunk == 3) && (wv == 3);   // pair 3 reaches t0=4064
  y = pair_f32(S, rowp, seg, 3, tail);
  const int t = seg + 3 * 64 + S.lid;
  if (!tail || t < TVALID) orow[WINDOW + t] = y;
}

extern "C" void kernel_launch(void* const* d_in, const int* in_sizes, int n_in,
                              void* d_out, int out_size, void* d_ws, size_t ws_size,
                              hipStream_t stream) {
  const float* ret = (const float*)d_in[0];
  const float* W1  = (const float*)d_in[1];
  const float* b1  = (const float*)d_in[2];
  const float* W2  = (const float*)d_in[3];
  const float* b2  = (const float*)d_in[4];
  float* out = (float*)d_out;

  const int B = in_sizes[0] / TDIM;          // 2048
  dim3 block(256);
  dim3 grid(B, 4);                           // 8192 blocks: 4x the wave count
  hipLaunchKernelGGL(hurst_tlp, grid, block, 0, stream,
                     ret, W1, b1, W2, b2, out);
}

// Round 9
// 44.088 us; speedup vs baseline: 1.2436x; 1.0673x over previous
//
#include <hip/hip_runtime.h>

#define WINDOW 10
#define TDIM 4096
#define TVALID (TDIM - WINDOW)   // 4086 valid outputs per row
#define LROW 4160                // LDS row: 4096 + 64 pad (last value replicated)

typedef __attribute__((ext_vector_type(8)))  short bf16x8;   // MFMA operand (4 VGPRs)
typedef __attribute__((ext_vector_type(8)))  __bf16 bfv8;
typedef __attribute__((ext_vector_type(8)))  float f32x8;
typedef __attribute__((ext_vector_type(16))) float f32x16;
typedef __attribute__((ext_vector_type(2)))  float f32x2;
typedef float f32x4u __attribute__((ext_vector_type(4), aligned(4)));
typedef float f32x4a __attribute__((ext_vector_type(4), aligned(16)));

static __device__ __forceinline__ short f2bf(float f) {
  return (short)__builtin_bit_cast(unsigned short, (__bf16)f);   // RNE
}

// layer-2 relu-dot: scalar v_max + packed v_pk_fma_f32
static __device__ __forceinline__ float l2dot(const f32x16& acc, const f32x2* __restrict__ w2p) {
  f32x2 s0 = {0.f, 0.f}, s1 = {0.f, 0.f};
  #pragma unroll
  for (int j = 0; j < 8; j += 2) {
    f32x2 a, b;
    a[0] = fmaxf(acc[2*j],     0.f); a[1] = fmaxf(acc[2*j + 1], 0.f);
    b[0] = fmaxf(acc[2*j + 2], 0.f); b[1] = fmaxf(acc[2*j + 3], 0.f);
    s0 = __builtin_elementwise_fma(a, w2p[j],     s0);
    s1 = __builtin_elementwise_fma(b, w2p[j + 1], s1);
  }
  f32x2 s = s0 + s1;
  return s[0] + s[1];
}

static __device__ __forceinline__ float combine_halves(float Pe, float Po, int lid) {
#if __has_builtin(__builtin_amdgcn_permlane32_swap)
  auto r = __builtin_amdgcn_permlane32_swap(
      __builtin_bit_cast(unsigned, Pe), __builtin_bit_cast(unsigned, Po), false, false);
  return __builtin_bit_cast(float, (unsigned)r[0]) + __builtin_bit_cast(float, (unsigned)r[1]);
#else
  Pe += __shfl_xor(Pe, 32, 64);
  Po += __shfl_xor(Po, 32, 64);
  return (lid < 32) ? Pe : Po;
#endif
}

static __device__ __forceinline__ float half_sigmoid(float z) {
  float e = __expf(-z);
#if __has_builtin(__builtin_amdgcn_rcpf)
  return 0.5f * __builtin_amdgcn_rcpf(1.0f + e);
#else
  return 0.5f / (1.0f + e);
#endif
}

struct Setup {
  bf16x8 af; f32x2 w2p[8]; float b2c;
  int lid, n, g; bool g1;
};
static __device__ __forceinline__ Setup make_setup(
    const float* __restrict__ W1, const float* __restrict__ b1,
    const float* __restrict__ W2, const float* __restrict__ b2) {
  Setup s;
  s.lid = threadIdx.x & 63; s.n = s.lid & 31; s.g = s.lid >> 5; s.g1 = (s.g == 1);
  if (!s.g1) {
    #pragma unroll
    for (int j = 0; j < 8; ++j) s.af[j] = f2bf(W1[s.n * WINDOW + j]);
  } else {
    s.af[0] = f2bf(W1[s.n * WINDOW + 8]);
    s.af[1] = f2bf(W1[s.n * WINDOW + 9]);
    s.af[2] = f2bf(b1[s.n]);                 // bias at k-slot 10
    #pragma unroll
    for (int j = 3; j < 8; ++j) s.af[j] = 0; // B k=11..15 don't-cares
  }
  #pragma unroll
  for (int j = 0; j < 8; ++j) {
    s.w2p[j][0] = W2[((2*j)   & 3) + 8 * ((2*j)   >> 2) + 4 * s.g];
    s.w2p[j][1] = W2[((2*j+1) & 3) + 8 * ((2*j+1) >> 2) + 4 * s.g];
  }
  s.b2c = b2[0];
  return s;
}

static __device__ __forceinline__ bf16x8 packbf(f32x8 f, bool g1) {
  f[2] = g1 ? 1.0f : f[2];           // bias column at k-slot 10
  return __builtin_bit_cast(bf16x8, __builtin_convertvector(f, bfv8));
}

// fragment from LDS: 8 consecutive f32 at arbitrary 4B-aligned offset
static __device__ __forceinline__ f32x8 lds_ld8(const float* __restrict__ p) {
  f32x8 f;
  #pragma unroll
  for (int j = 0; j < 8; ++j) f[j] = p[j];   // -> ds_read2_b32 / ds_read_b64 mix
  return f;
}

// one tile-pair (64 outputs) entirely from LDS
static __device__ __forceinline__ float pair_lds(
    const Setup& S, const float* __restrict__ srow, int seg, int p) {
  const float* base = srow + seg + p * 64 + S.n + 8 * S.g;
  f32x8 fe = lds_ld8(base);
  f32x8 fo = lds_ld8(base + 32);
  bf16x8 bve = packbf(fe, S.g1), bvo = packbf(fo, S.g1);
  f32x16 acce = {}, acco = {};
  acce = __builtin_amdgcn_mfma_f32_32x32x16_bf16(S.af, bve, acce, 0, 0, 0);
  acco = __builtin_amdgcn_mfma_f32_32x32x16_bf16(S.af, bvo, acco, 0, 0, 0);
  float Pe = l2dot(acce, S.w2p);
  float Po = l2dot(acco, S.w2p);
  const float q = combine_halves(Pe, Po, S.lid);
  return half_sigmoid(q + S.b2c);
}

__global__ __launch_bounds__(256) void hurst_lds(
    const float* __restrict__ ret, const float* __restrict__ W1,
    const float* __restrict__ b1,  const float* __restrict__ W2,
    const float* __restrict__ b2,  float* __restrict__ out) {
  __shared__ float srow[LROW];

  const int row = blockIdx.x;
  const float* __restrict__ rowp = ret + (size_t)row * TDIM;
  float* __restrict__ orow = out + (size_t)row * TDIM;

  // ---- stage whole row into LDS: coalesced dwordx4, all loads issued upfront ----
  {
    const int tid = threadIdx.x;
    // c in {tid, tid+256, tid+512(<520)}: 8 floats per chunk
    #pragma unroll
    for (int it = 0; it < 3; ++it) {
      const int c = tid + it * 256;
      if (c < LROW / 8) {
        f32x8 f;
        if (c < TDIM / 8) {
          f32x4u a = *(const f32x4u*)(rowp + 8 * c);
          f32x4u b = *(const f32x4u*)(rowp + 8 * c + 4);
          f[0]=a[0]; f[1]=a[1]; f[2]=a[2]; f[3]=a[3];
          f[4]=b[0]; f[5]=b[1]; f[6]=b[2]; f[7]=b[3];
        } else {
          const float last = rowp[TDIM - 1];
          #pragma unroll
          for (int j = 0; j < 8; ++j) f[j] = last;   // replicate-pad
        }
        f32x4a lo = {f[0], f[1], f[2], f[3]};
        f32x4a hi = {f[4], f[5], f[6], f[7]};
        *(f32x4a*)(srow + 8 * c)     = lo;           // ds_write_b128 (16B aligned)
        *(f32x4a*)(srow + 8 * c + 4) = hi;
      }
    }
  }

  Setup S = make_setup(W1, b1, W2, b2);   // overlaps with staging latency
  __syncthreads();

  const int wv  = threadIdx.x >> 6;
  const int seg = wv * 1024;

  float y = pair_lds(S, srow, seg, 0);
  orow[WINDOW + seg + S.lid] = y;
  if (wv == 0) {                           // head broadcast, once per row
    const float y0 = __shfl(y, 0, 64);
    if (S.lid < WINDOW) orow[S.lid] = y0;
  }
  #pragma unroll
  for (int p = 1; p < 15; ++p) {
    y = pair_lds(S, srow, seg, p);
    orow[WINDOW + seg + p * 64 + S.lid] = y;
  }
  y = pair_lds(S, srow, seg, 15);          // loads hit replicate-pad; mask stores
  const int t = seg + 15 * 64 + S.lid;
  if (t < TVALID) orow[WINDOW + t] = y;
}

extern "C" void kernel_launch(void* const* d_in, const int* in_sizes, int n_in,
                              void* d_out, int out_size, void* d_ws, size_t ws_size,
                              hipStream_t stream) {
  const float* ret = (const float*)d_in[0];
  const float* W1  = (const float*)d_in[1];
  const float* b1  = (const float*)d_in[2];
  const float* W2  = (const float*)d_in[3];
  const float* b2  = (const float*)d_in[4];
  float* out = (float*)d_out;

  const int B = in_sizes[0] / TDIM;        // 2048
  dim3 block(256);                         // 4 waves x 1024-wide segments
  dim3 grid(B);
  hipLaunchKernelGGL(hurst_lds, grid, block, 0, stream,
                     ret, W1, b1, W2, b2, out);
}

// Round 10
// 43.412 us; speedup vs baseline: 1.2630x; 1.0156x over previous
//
#include <hip/hip_runtime.h>

#define WINDOW 10
#define TDIM 4096
#define TVALID (TDIM - WINDOW)   // 4086 valid outputs per row
#define LROW 4160                // LDS row: 4096 + 64 pad (last value replicated)

typedef __attribute__((ext_vector_type(8)))  short bf16x8;   // MFMA operand (4 VGPRs)
typedef __attribute__((ext_vector_type(8)))  __bf16 bfv8;
typedef __attribute__((ext_vector_type(8)))  float f32x8;
typedef __attribute__((ext_vector_type(16))) float f32x16;
typedef __attribute__((ext_vector_type(2)))  float f32x2;
typedef float f32x4u __attribute__((ext_vector_type(4), aligned(4)));
typedef float f32x4a __attribute__((ext_vector_type(4), aligned(16)));

static __device__ __forceinline__ short f2bf(float f) {
  return (short)__builtin_bit_cast(unsigned short, (__bf16)f);   // RNE
}

// layer-2 relu-dot: scalar v_max + packed v_pk_fma_f32
static __device__ __forceinline__ float l2dot(const f32x16& acc, const f32x2* __restrict__ w2p) {
  f32x2 s0 = {0.f, 0.f}, s1 = {0.f, 0.f};
  #pragma unroll
  for (int j = 0; j < 8; j += 2) {
    f32x2 a, b;
    a[0] = fmaxf(acc[2*j],     0.f); a[1] = fmaxf(acc[2*j + 1], 0.f);
    b[0] = fmaxf(acc[2*j + 2], 0.f); b[1] = fmaxf(acc[2*j + 3], 0.f);
    s0 = __builtin_elementwise_fma(a, w2p[j],     s0);
    s1 = __builtin_elementwise_fma(b, w2p[j + 1], s1);
  }
  f32x2 s = s0 + s1;
  return s[0] + s[1];
}

static __device__ __forceinline__ float combine_halves(float Pe, float Po, int lid) {
#if __has_builtin(__builtin_amdgcn_permlane32_swap)
  auto r = __builtin_amdgcn_permlane32_swap(
      __builtin_bit_cast(unsigned, Pe), __builtin_bit_cast(unsigned, Po), false, false);
  return __builtin_bit_cast(float, (unsigned)r[0]) + __builtin_bit_cast(float, (unsigned)r[1]);
#else
  Pe += __shfl_xor(Pe, 32, 64);
  Po += __shfl_xor(Po, 32, 64);
  return (lid < 32) ? Pe : Po;
#endif
}

static __device__ __forceinline__ float half_sigmoid(float z) {
  float e = __expf(-z);
#if __has_builtin(__builtin_amdgcn_rcpf)
  return 0.5f * __builtin_amdgcn_rcpf(1.0f + e);
#else
  return 0.5f / (1.0f + e);
#endif
}

struct Setup {
  bf16x8 af;        // W1 taps only; k-slots 10..15 zero (B there is don't-care)
  f32x16 cinit;     // loop-invariant C operand: C[m][n] = b1[m]  (bias via MFMA C)
  f32x2  w2p[8];
  float  b2c;
  int lid, n, g;
};
static __device__ __forceinline__ Setup make_setup(
    const float* __restrict__ W1, const float* __restrict__ b1,
    const float* __restrict__ W2, const float* __restrict__ b2) {
  Setup s;
  s.lid = threadIdx.x & 63; s.n = s.lid & 31; s.g = s.lid >> 5;
  const bool g1 = (s.g == 1);
  if (!g1) {
    #pragma unroll
    for (int j = 0; j < 8; ++j) s.af[j] = f2bf(W1[s.n * WINDOW + j]);
  } else {
    s.af[0] = f2bf(W1[s.n * WINDOW + 8]);
    s.af[1] = f2bf(W1[s.n * WINDOW + 9]);
    #pragma unroll
    for (int j = 2; j < 8; ++j) s.af[j] = 0;   // no bias column needed anymore
  }
  // D/C row map: m(r) = (r&3) + 8*(r>>2) + 4*g  (HW-verified)
  #pragma unroll
  for (int r = 0; r < 16; ++r) s.cinit[r] = b1[(r & 3) + 8 * (r >> 2) + 4 * s.g];
  #pragma unroll
  for (int j = 0; j < 8; ++j) {
    s.w2p[j][0] = W2[((2*j)   & 3) + 8 * ((2*j)   >> 2) + 4 * s.g];
    s.w2p[j][1] = W2[((2*j+1) & 3) + 8 * ((2*j+1) >> 2) + 4 * s.g];
  }
  s.b2c = b2[0];
  return s;
}

// one tile-pair (64 outputs) from LDS; no per-tile C materialization, no bias fixup
static __device__ __forceinline__ float pair_lds(const Setup& S, const float* __restrict__ base) {
  f32x8 fe, fo;
  #pragma unroll
  for (int j = 0; j < 8; ++j) fe[j] = base[j];
  #pragma unroll
  for (int j = 0; j < 8; ++j) fo[j] = base[32 + j];
  bf16x8 bve = __builtin_bit_cast(bf16x8, __builtin_convertvector(fe, bfv8));
  bf16x8 bvo = __builtin_bit_cast(bf16x8, __builtin_convertvector(fo, bfv8));
  f32x16 acce = __builtin_amdgcn_mfma_f32_32x32x16_bf16(S.af, bve, S.cinit, 0, 0, 0);
  float Pe = l2dot(acce, S.w2p);
  f32x16 acco = __builtin_amdgcn_mfma_f32_32x32x16_bf16(S.af, bvo, S.cinit, 0, 0, 0);
  float Po = l2dot(acco, S.w2p);
  const float q = combine_halves(Pe, Po, S.lid);
  return half_sigmoid(q + S.b2c);
}

__global__ __launch_bounds__(256) void hurst_lds2(
    const float* __restrict__ ret, const float* __restrict__ W1,
    const float* __restrict__ b1,  const float* __restrict__ W2,
    const float* __restrict__ b2,  float* __restrict__ out) {
  __shared__ float srow[LROW];

  const int row = blockIdx.x;
  const float* __restrict__ rowp = ret + (size_t)row * TDIM;
  float* __restrict__ orow = out + (size_t)row * TDIM;

  // ---- stage whole row into LDS: coalesced dwordx4, all loads issued upfront ----
  {
    const int tid = threadIdx.x;
    #pragma unroll
    for (int it = 0; it < 3; ++it) {
      const int c = tid + it * 256;
      if (c < LROW / 8) {
        f32x8 f;
        if (c < TDIM / 8) {
          f32x4u a = *(const f32x4u*)(rowp + 8 * c);
          f32x4u b = *(const f32x4u*)(rowp + 8 * c + 4);
          f[0]=a[0]; f[1]=a[1]; f[2]=a[2]; f[3]=a[3];
          f[4]=b[0]; f[5]=b[1]; f[6]=b[2]; f[7]=b[3];
        } else {
          const float last = rowp[TDIM - 1];
          #pragma unroll
          for (int j = 0; j < 8; ++j) f[j] = last;   // replicate-pad
        }
        f32x4a lo = {f[0], f[1], f[2], f[3]};
        f32x4a hi = {f[4], f[5], f[6], f[7]};
        *(f32x4a*)(srow + 8 * c)     = lo;           // ds_write_b128
        *(f32x4a*)(srow + 8 * c + 4) = hi;
      }
    }
  }

  Setup S = make_setup(W1, b1, W2, b2);   // gathers overlap staging latency
  __syncthreads();

  const int wv  = threadIdx.x >> 6;
  const int seg = wv * 1024;
  const float* __restrict__ lbase = srow + seg + S.n + 8 * S.g;

  float y = pair_lds(S, lbase);
  orow[WINDOW + seg + S.lid] = y;
  if (wv == 0) {                           // head broadcast, once per row
    const float y0 = __shfl(y, 0, 64);
    if (S.lid < WINDOW) orow[S.lid] = y0;
  }
  #pragma unroll
  for (int p = 1; p < 15; ++p) {
    y = pair_lds(S, lbase + p * 64);
    orow[WINDOW + seg + p * 64 + S.lid] = y;
  }
  y = pair_lds(S, lbase + 15 * 64);        // reads hit replicate-pad; mask stores
  const int t = seg + 15 * 64 + S.lid;
  if (t < TVALID) orow[WINDOW + t] = y;
}

extern "C" void kernel_launch(void* const* d_in, const int* in_sizes, int n_in,
                              void* d_out, int out_size, void* d_ws, size_t ws_size,
                              hipStream_t stream) {
  const float* ret = (const float*)d_in[0];
  const float* W1  = (const float*)d_in[1];
  const float* b1  = (const float*)d_in[2];
  const float* W2  = (const float*)d_in[3];
  const float* b2  = (const float*)d_in[4];
  float* out = (float*)d_out;

  const int B = in_sizes[0] / TDIM;        // 2048
  dim3 block(256);                         // 4 waves x 1024-wide segments
  dim3 grid(B);
  hipLaunchKernelGGL(hurst_lds2, grid, block, 0, stream,
                     ret, W1, b1, W2, b2, out);
}

// Round 11
// 42.772 us; speedup vs baseline: 1.2819x; 1.0150x over previous
//
#include <hip/hip_runtime.h>

#define WINDOW 10
#define TDIM 4096
#define TVALID (TDIM - WINDOW)   // 4086 valid outputs per row
#define LROW 4160                // LDS row: 4096 + 64 pad (last value replicated)

typedef __attribute__((ext_vector_type(8)))  short bf16x8;   // MFMA operand (4 VGPRs)
typedef __attribute__((ext_vector_type(8)))  __bf16 bfv8;
typedef __attribute__((ext_vector_type(8)))  float f32x8;
typedef __attribute__((ext_vector_type(16))) float f32x16;
typedef __attribute__((ext_vector_type(2)))  float f32x2;
typedef float f32x4u __attribute__((ext_vector_type(4), aligned(4)));
typedef float f32x4a __attribute__((ext_vector_type(4), aligned(16)));

static __device__ __forceinline__ short f2bf(float f) {
  return (short)__builtin_bit_cast(unsigned short, (__bf16)f);   // RNE
}

static __device__ __forceinline__ float combine_halves(float Pe, float Po, int lid) {
#if __has_builtin(__builtin_amdgcn_permlane32_swap)
  auto r = __builtin_amdgcn_permlane32_swap(
      __builtin_bit_cast(unsigned, Pe), __builtin_bit_cast(unsigned, Po), false, false);
  return __builtin_bit_cast(float, (unsigned)r[0]) + __builtin_bit_cast(float, (unsigned)r[1]);
#else
  Pe += __shfl_xor(Pe, 32, 64);
  Po += __shfl_xor(Po, 32, 64);
  return (lid < 32) ? Pe : Po;
#endif
}

static __device__ __forceinline__ float half_sigmoid(float z) {
  float e = __expf(-z);
#if __has_builtin(__builtin_amdgcn_rcpf)
  return 0.5f * __builtin_amdgcn_rcpf(1.0f + e);
#else
  return 0.5f / (1.0f + e);
#endif
}

struct Setup {
  bf16x8 af;        // W1 taps; k-slots 10..15 zero (B there is don't-care)
  f32x16 cinit;     // C[m][n] = b1[m] — bias via MFMA C operand
  f32x2  w2p[8];
  float  b2c;
  int lid, n, g;
};
static __device__ __forceinline__ Setup make_setup(
    const float* __restrict__ W1, const float* __restrict__ b1,
    const float* __restrict__ W2, const float* __restrict__ b2) {
  Setup s;
  s.lid = threadIdx.x & 63; s.n = s.lid & 31; s.g = s.lid >> 5;
  const bool g1 = (s.g == 1);
  if (!g1) {
    #pragma unroll
    for (int j = 0; j < 8; ++j) s.af[j] = f2bf(W1[s.n * WINDOW + j]);
  } else {
    s.af[0] = f2bf(W1[s.n * WINDOW + 8]);
    s.af[1] = f2bf(W1[s.n * WINDOW + 9]);
    #pragma unroll
    for (int j = 2; j < 8; ++j) s.af[j] = 0;
  }
  // D/C row map: m(r) = (r&3) + 8*(r>>2) + 4*g  (HW-verified)
  #pragma unroll
  for (int r = 0; r < 16; ++r) s.cinit[r] = b1[(r & 3) + 8 * (r >> 2) + 4 * s.g];
  #pragma unroll
  for (int j = 0; j < 8; ++j) {
    s.w2p[j][0] = W2[((2*j)   & 3) + 8 * ((2*j)   >> 2) + 4 * s.g];
    s.w2p[j][1] = W2[((2*j+1) & 3) + 8 * ((2*j+1) >> 2) + 4 * s.g];
  }
  s.b2c = b2[0];
  return s;
}

static __device__ __forceinline__ f32x8 lds_ld8(const float* __restrict__ p) {
  f32x8 f;
  #pragma unroll
  for (int j = 0; j < 8; ++j) f[j] = p[j];
  return f;
}
static __device__ __forceinline__ bf16x8 cvt8(const f32x8& f) {
  return __builtin_bit_cast(bf16x8, __builtin_convertvector(f, bfv8));
}
static __device__ __forceinline__ f32x2 relu2(float x, float y) {
  f32x2 v = {x, y};
  const f32x2 z2 = {0.f, 0.f};
  return __builtin_elementwise_max(v, z2);   // v_pk_max_f32
}

__global__ __launch_bounds__(256) void hurst_ilp4(
    const float* __restrict__ ret, const float* __restrict__ W1,
    const float* __restrict__ b1,  const float* __restrict__ W2,
    const float* __restrict__ b2,  float* __restrict__ out) {
  __shared__ float srow[LROW];

  const int row = blockIdx.x;
  const float* __restrict__ rowp = ret + (size_t)row * TDIM;
  float* __restrict__ orow = out + (size_t)row * TDIM;

  // ---- stage whole row into LDS: coalesced dwordx4, all loads issued upfront ----
  {
    const int tid = threadIdx.x;
    #pragma unroll
    for (int it = 0; it < 3; ++it) {
      const int c = tid + it * 256;
      if (c < LROW / 8) {
        f32x8 f;
        if (c < TDIM / 8) {
          f32x4u a = *(const f32x4u*)(rowp + 8 * c);
          f32x4u b = *(const f32x4u*)(rowp + 8 * c + 4);
          f[0]=a[0]; f[1]=a[1]; f[2]=a[2]; f[3]=a[3];
          f[4]=b[0]; f[5]=b[1]; f[6]=b[2]; f[7]=b[3];
        } else {
          const float last = rowp[TDIM - 1];
          #pragma unroll
          for (int j = 0; j < 8; ++j) f[j] = last;   // replicate-pad
        }
        f32x4a lo = {f[0], f[1], f[2], f[3]};
        f32x4a hi = {f[4], f[5], f[6], f[7]};
        *(f32x4a*)(srow + 8 * c)     = lo;           // ds_write_b128
        *(f32x4a*)(srow + 8 * c + 4) = hi;
      }
    }
  }

  Setup S = make_setup(W1, b1, W2, b2);   // overlaps staging latency
  __syncthreads();

  const int wv  = threadIdx.x >> 6;
  const int seg = wv * 1024;
  const float* __restrict__ lbase = srow + seg + S.n + 8 * S.g;

  // ---- 8 quads; each quad = 4 tiles = 128 outputs with 4-way in-wave ILP ----
  #pragma unroll 1
  for (int q = 0; q < 8; ++q) {
    const float* qb = lbase + q * 128;

    // phase L+C: 4 fragments
    bf16x8 bvA = cvt8(lds_ld8(qb));
    bf16x8 bvB = cvt8(lds_ld8(qb + 32));
    bf16x8 bvC = cvt8(lds_ld8(qb + 64));
    bf16x8 bvD = cvt8(lds_ld8(qb + 96));

    // phase M: 4 independent MFMAs, issued back-to-back
    f32x16 aA = __builtin_amdgcn_mfma_f32_32x32x16_bf16(S.af, bvA, S.cinit, 0, 0, 0);
    f32x16 aB = __builtin_amdgcn_mfma_f32_32x32x16_bf16(S.af, bvB, S.cinit, 0, 0, 0);
    f32x16 aC = __builtin_amdgcn_mfma_f32_32x32x16_bf16(S.af, bvC, S.cinit, 0, 0, 0);
    f32x16 aD = __builtin_amdgcn_mfma_f32_32x32x16_bf16(S.af, bvD, S.cinit, 0, 0, 0);

    // phase D: interlocked l2dot — every j touches all 4 accs, so all 4 MFMA
    // results are live simultaneously (compiler cannot re-serialize per tile)
    f32x2 sA0={0.f,0.f}, sA1={0.f,0.f}, sB0={0.f,0.f}, sB1={0.f,0.f};
    f32x2 sC0={0.f,0.f}, sC1={0.f,0.f}, sD0={0.f,0.f}, sD1={0.f,0.f};
    #pragma unroll
    for (int j = 0; j < 8; j += 2) {
      sA0 = __builtin_elementwise_fma(relu2(aA[2*j],   aA[2*j+1]), S.w2p[j],   sA0);
      sB0 = __builtin_elementwise_fma(relu2(aB[2*j],   aB[2*j+1]), S.w2p[j],   sB0);
      sC0 = __builtin_elementwise_fma(relu2(aC[2*j],   aC[2*j+1]), S.w2p[j],   sC0);
      sD0 = __builtin_elementwise_fma(relu2(aD[2*j],   aD[2*j+1]), S.w2p[j],   sD0);
      sA1 = __builtin_elementwise_fma(relu2(aA[2*j+2], aA[2*j+3]), S.w2p[j+1], sA1);
      sB1 = __builtin_elementwise_fma(relu2(aB[2*j+2], aB[2*j+3]), S.w2p[j+1], sB1);
      sC1 = __builtin_elementwise_fma(relu2(aC[2*j+2], aC[2*j+3]), S.w2p[j+1], sC1);
      sD1 = __builtin_elementwise_fma(relu2(aD[2*j+2], aD[2*j+3]), S.w2p[j+1], sD1);
    }
    f32x2 sA = sA0 + sA1, sB = sB0 + sB1, sC = sC0 + sC1, sD = sD0 + sD1;
    float PA = sA[0] + sA[1], PB = sB[0] + sB[1];
    float PC = sC[0] + sC[1], PD = sD[0] + sD[1];

    const float q0 = combine_halves(PA, PB, S.lid);   // pair 0: tiles A,B
    const float q1 = combine_halves(PC, PD, S.lid);   // pair 1: tiles C,D
    const float y0 = half_sigmoid(q0 + S.b2c);
    const float y1 = half_sigmoid(q1 + S.b2c);

    const int t0 = seg + q * 128 + S.lid;
    const int t1 = t0 + 64;
    orow[WINDOW + t0] = y0;                 // always valid (t0 <= 4031+... < TVALID)
    if (t1 < TVALID) orow[WINDOW + t1] = y1;

    if (q == 0 && wv == 0) {                // head broadcast, once per row
      const float yh = __shfl(y0, 0, 64);
      if (S.lid < WINDOW) orow[S.lid] = yh;
    }
  }
}

extern "C" void kernel_launch(void* const* d_in, const int* in_sizes, int n_in,
                              void* d_out, int out_size, void* d_ws, size_t ws_size,
                              hipStream_t stream) {
  const float* ret = (const float*)d_in[0];
  const float* W1  = (const float*)d_in[1];
  const float* b1  = (const float*)d_in[2];
  const float* W2  = (const float*)d_in[3];
  const float* b2  = (const float*)d_in[4];
  float* out = (float*)d_out;

  const int B = in_sizes[0] / TDIM;        // 2048
  dim3 block(256);                         // 4 waves x 1024-wide segments
  dim3 grid(B);
  hipLaunchKernelGGL(hurst_ilp4, grid, block, 0, stream,
                     ret, W1, b1, W2, b2, out);
}